// Round 1
// baseline (124.438 us; speedup 1.0000x reference)
//
#include <hip/hip_runtime.h>

#define N 4096
#define BLK 256
#define NEGF (-3.4e38f)

// 4B-aligned float4 (multi-dword global loads need only dword alignment on CDNA).
typedef float f4u __attribute__((ext_vector_type(4), aligned(4)));
typedef float f4a __attribute__((ext_vector_type(4), aligned(16)));

// Single pass over one tril row: two running maxes (mask is exactly {0,1}):
//   bc = max score over mask==1, sm = max ana score over mask==0 (j<row).
// 4 independent accumulator pairs break the dependent fmax chain (ILP);
// nontemporal loads: data is single-use, don't fight the harness fill's
// writeback for L2/L3 lines.
__device__ __forceinline__ void scan_row(
    const float* __restrict__ ana_scores,
    const float* __restrict__ mask,
    const int row, const int tid,
    float& bc_out, float& sm_out)
{
    const long long base = (long long)row * (row - 1) / 2;
    const float* __restrict__ arow = ana_scores + base;
    const float* __restrict__ mrow = mask + (size_t)row * (size_t)N;

    float bc0 = NEGF, bc1 = NEGF, bc2 = NEGF, bc3 = NEGF;
    float sm0 = NEGF, sm1 = NEGF, sm2 = NEGF, sm3 = NEGF;

    // Peel so ana + base + p is 16B-aligned.
    int p = (int)((4 - (base & 3)) & 3);
    if (p > row) p = row;
    const int nvec = (row - p) >> 2;      // float4 groups in [p, p+4*nvec)
    const int t0   = p + (nvec << 2);     // tail start

#pragma unroll 4
    for (int g = tid; g < nvec; g += BLK) {
        const int j = p + (g << 2);
        const f4a s4 = __builtin_nontemporal_load((const f4a*)(arow + j));
        const f4u m4 = __builtin_nontemporal_load((const f4u*)(mrow + j));
        const bool o0 = (m4[0] != 0.0f);
        const bool o1 = (m4[1] != 0.0f);
        const bool o2 = (m4[2] != 0.0f);
        const bool o3 = (m4[3] != 0.0f);
        bc0 = fmaxf(bc0, o0 ? s4[0] : NEGF);
        sm0 = fmaxf(sm0, o0 ? NEGF : s4[0]);
        bc1 = fmaxf(bc1, o1 ? s4[1] : NEGF);
        sm1 = fmaxf(sm1, o1 ? NEGF : s4[1]);
        bc2 = fmaxf(bc2, o2 ? s4[2] : NEGF);
        sm2 = fmaxf(sm2, o2 ? NEGF : s4[2]);
        bc3 = fmaxf(bc3, o3 ? s4[3] : NEGF);
        sm3 = fmaxf(sm3, o3 ? NEGF : s4[3]);
    }
    // Scalar peel [0,p) and tail [t0,row): <=3 elems each.
    if (tid < p) {
        const float s = arow[tid], m = mrow[tid];
        if (m != 0.0f) bc0 = fmaxf(bc0, s); else sm0 = fmaxf(sm0, s);
    }
    if (tid < row - t0) {
        const int j = t0 + tid;
        const float s = arow[j], m = mrow[j];
        if (m != 0.0f) bc1 = fmaxf(bc1, s); else sm1 = fmaxf(sm1, s);
    }
    bc_out = fmaxf(fmaxf(bc0, bc1), fmaxf(bc2, bc3));
    sm_out = fmaxf(fmaxf(sm0, sm1), fmaxf(sm2, sm3));
}

__device__ __forceinline__ float row_loss(
    float B, float S, const float e, const float d,
    const float lc0, const float lc1, const float fn)
{
    if (d != 0.0f) B = fmaxf(B, e);            // epsilon is a correct antecedent
    const float rc = d * lc0 + (1.0f - d) * lc1;
    float loss = fmaxf(0.0f, rc * (1.0f + S - B));
    if (d == 0.0f) loss = fmaxf(loss, fn * (1.0f + e - B));
    return loss;
}

// Balanced pairing: block b handles rows (N-1-b, b) -> exactly N-1 elements
// per block, every block identical length; one joint reduction + epilogue.
__global__ __launch_bounds__(BLK) void mention_loss_kernel(
    const float* __restrict__ eps_scores,
    const float* __restrict__ ana_scores,
    const float* __restrict__ mask,
    const float* __restrict__ link_costs,
    const float* __restrict__ false_new_cost,
    float* __restrict__ out)
{
    const int b    = (int)blockIdx.x;
    const int rowA = N - 1 - b;   // long row  (2048..4095)
    const int rowB = b;           // short row (0..2047)
    const int tid  = threadIdx.x;

    float bcA, smA, bcB, smB;
    scan_row(ana_scores, mask, rowA, tid, bcA, smA);
    scan_row(ana_scores, mask, rowB, tid, bcB, smB);

    // Joint wave butterfly for both rows' (bc, sm).
    for (int off = 32; off; off >>= 1) {
        bcA = fmaxf(bcA, __shfl_down(bcA, off));
        smA = fmaxf(smA, __shfl_down(smA, off));
        bcB = fmaxf(bcB, __shfl_down(bcB, off));
        smB = fmaxf(smB, __shfl_down(smB, off));
    }
    __shared__ float r[4][BLK / 64];
    if ((tid & 63) == 0) {
        const int w = tid >> 6;
        r[0][w] = bcA; r[1][w] = smA; r[2][w] = bcB; r[3][w] = smB;
    }
    __syncthreads();
    if (tid == 0) {
        float BA = r[0][0], SA = r[1][0], BB = r[2][0], SB = r[3][0];
#pragma unroll
        for (int w = 1; w < BLK / 64; ++w) {
            BA = fmaxf(BA, r[0][w]); SA = fmaxf(SA, r[1][w]);
            BB = fmaxf(BB, r[2][w]); SB = fmaxf(SB, r[3][w]);
        }
        const float lc0 = link_costs[0], lc1 = link_costs[1];
        const float fn  = false_new_cost[0];
        const float eA = eps_scores[rowA];
        const float dA = mask[(size_t)rowA * N + rowA];
        const float eB = eps_scores[rowB];
        const float dB = mask[(size_t)rowB * N + rowB];
        out[rowA] = row_loss(BA, SA, eA, dA, lc0, lc1, fn);
        out[rowB] = row_loss(BB, SB, eB, dB, lc0, lc1, fn);
    }
}

extern "C" void kernel_launch(void* const* d_in, const int* in_sizes, int n_in,
                              void* d_out, int out_size, void* d_ws, size_t ws_size,
                              hipStream_t stream) {
    const float* eps  = (const float*)d_in[0];
    const float* ana  = (const float*)d_in[1];
    const float* mask = (const float*)d_in[2];
    const float* lc   = (const float*)d_in[3];
    const float* fnc  = (const float*)d_in[4];
    float* out = (float*)d_out;

    mention_loss_kernel<<<N / 2, BLK, 0, stream>>>(eps, ana, mask, lc, fnc, out);
}

// Round 2
// 117.243 us; speedup vs baseline: 1.0614x; 1.0614x over previous
//
#include <hip/hip_runtime.h>

#define N 4096
#define BLK 256
#define NEGF (-3.4e38f)

// 4B-aligned float4 (multi-dword global loads need only dword alignment on CDNA).
typedef float f4u __attribute__((ext_vector_type(4), aligned(4)));
typedef float f4a __attribute__((ext_vector_type(4), aligned(16)));

// Single-pass, two running maxes per row (mask is exactly {0,1}):
//   bc = max over {m=1} of score     (ref's global min is dead code)
//   sm = max over {m=0, j<row} of ana score
//   loss = max(0, rc*(1+sm-bc), (d==0)*fn*(1+eps-bc))
// 4 independent accumulator pairs + branchless selects: no dependent fmax
// chain longer than nvec/BLK iterations per accumulator.
__global__ __launch_bounds__(BLK) void mention_loss_kernel(
    const float* __restrict__ eps_scores,
    const float* __restrict__ ana_scores,
    const float* __restrict__ mask,
    const float* __restrict__ link_costs,
    const float* __restrict__ false_new_cost,
    float* __restrict__ out)
{
    // Longest rows first: blockIdx 0 -> row N-1.
    const int row = N - 1 - (int)blockIdx.x;
    const int tid = threadIdx.x;
    const long long base = (long long)row * (row - 1) / 2;
    const float* __restrict__ arow = ana_scores + base;
    const float* __restrict__ mrow = mask + (size_t)row * (size_t)N;

    float bc0 = NEGF, bc1 = NEGF, bc2 = NEGF, bc3 = NEGF;
    float sm0 = NEGF, sm1 = NEGF, sm2 = NEGF, sm3 = NEGF;

    // Peel so ana_scores + base + p is 16B-aligned.
    int p = (int)((4 - (base & 3)) & 3);
    if (p > row) p = row;
    const int nvec = (row - p) >> 2;          // float4 groups in [p, p+4*nvec)
    const int t0   = p + (nvec << 2);         // tail start

    // Vectorized main: 4 elems/lane/iter, dwordx4 on both streams.
    // unroll 4 -> up to 8 independent dwordx4 in flight per thread.
#pragma unroll 4
    for (int g = tid; g < nvec; g += BLK) {
        const int j = p + (g << 2);
        const f4a s4 = *(const f4a*)(arow + j);   // 16B aligned
        const f4u m4 = *(const f4u*)(mrow + j);   // 4B aligned
        const bool o0 = (m4[0] != 0.0f);
        const bool o1 = (m4[1] != 0.0f);
        const bool o2 = (m4[2] != 0.0f);
        const bool o3 = (m4[3] != 0.0f);
        bc0 = fmaxf(bc0, o0 ? s4[0] : NEGF);
        sm0 = fmaxf(sm0, o0 ? NEGF : s4[0]);
        bc1 = fmaxf(bc1, o1 ? s4[1] : NEGF);
        sm1 = fmaxf(sm1, o1 ? NEGF : s4[1]);
        bc2 = fmaxf(bc2, o2 ? s4[2] : NEGF);
        sm2 = fmaxf(sm2, o2 ? NEGF : s4[2]);
        bc3 = fmaxf(bc3, o3 ? s4[3] : NEGF);
        sm3 = fmaxf(sm3, o3 ? NEGF : s4[3]);
    }
    // Scalar peel [0,p) and tail [t0,row): <=3 elems each.
    if (tid < p) {
        const float s = arow[tid], m = mrow[tid];
        if (m != 0.0f) bc0 = fmaxf(bc0, s); else sm0 = fmaxf(sm0, s);
    }
    if (tid < row - t0) {
        const int j = t0 + tid;
        const float s = arow[j], m = mrow[j];
        if (m != 0.0f) bc1 = fmaxf(bc1, s); else sm1 = fmaxf(sm1, s);
    }
    float bc = fmaxf(fmaxf(bc0, bc1), fmaxf(bc2, bc3));
    float sm = fmaxf(fmaxf(sm0, sm1), fmaxf(sm2, sm3));

    // Wave butterfly, then cross-wave LDS reduce.
    for (int off = 32; off; off >>= 1) {
        bc = fmaxf(bc, __shfl_down(bc, off));
        sm = fmaxf(sm, __shfl_down(sm, off));
    }
    __shared__ float r_bc[BLK / 64], r_sm[BLK / 64];
    if ((tid & 63) == 0) { r_bc[tid >> 6] = bc; r_sm[tid >> 6] = sm; }
    __syncthreads();
    if (tid == 0) {
        float B = r_bc[0], S = r_sm[0];
#pragma unroll
        for (int w = 1; w < BLK / 64; ++w) {
            B = fmaxf(B, r_bc[w]);
            S = fmaxf(S, r_sm[w]);
        }
        const float e = eps_scores[row];
        const float d = mrow[row];                 // diag of solution mask
        if (d != 0.0f) B = fmaxf(B, e);            // epsilon is a correct antecedent
        const float rc = d * link_costs[0] + (1.0f - d) * link_costs[1];
        float loss = fmaxf(0.0f, rc * (1.0f + S - B));
        if (d == 0.0f) loss = fmaxf(loss, false_new_cost[0] * (1.0f + e - B));
        out[row] = loss;
    }
}

extern "C" void kernel_launch(void* const* d_in, const int* in_sizes, int n_in,
                              void* d_out, int out_size, void* d_ws, size_t ws_size,
                              hipStream_t stream) {
    const float* eps  = (const float*)d_in[0];
    const float* ana  = (const float*)d_in[1];
    const float* mask = (const float*)d_in[2];
    const float* lc   = (const float*)d_in[3];
    const float* fnc  = (const float*)d_in[4];
    float* out = (float*)d_out;

    mention_loss_kernel<<<N, BLK, 0, stream>>>(eps, ana, mask, lc, fnc, out);
}